// Round 9
// baseline (267.617 us; speedup 1.0000x reference)
//
#include <hip/hip_runtime.h>

#define HID 256
#define PROJ 256
#define DYN 64
#define HWD 6400
#define BSZ 16
#define NQ 100
#define HH 80
#define WW 80

typedef unsigned short u16;
typedef u16 u16x8 __attribute__((ext_vector_type(8)));
typedef __bf16 bf16x8 __attribute__((ext_vector_type(8)));
typedef float f32x4 __attribute__((ext_vector_type(4)));

__device__ __forceinline__ float bf2f(u16 h) {
    union { unsigned u; float f; } c; c.u = ((unsigned)h) << 16; return c.f;
}
__device__ __forceinline__ u16 f2bf(float f) {
    union { float f; unsigned u; } c; c.f = f;
    return (u16)((c.u + 0x7FFFu + ((c.u >> 16) & 1u)) >> 16);
}

// ---------------------------------------------------------------------------
// K1 v3 (unchanged): 1024 thr, 4-way K-split, pinned weight batches.
// ---------------------------------------------------------------------------
__global__ __launch_bounds__(1024, 1) void kpre(
    const float* __restrict__ support,   // [100][16][256] f32
    const float* __restrict__ Wq, const float* __restrict__ bq,
    const float* __restrict__ Ws, const float* __restrict__ bsp,
    const float* __restrict__ W1, const float* __restrict__ b1,
    const float* __restrict__ W2, const float* __restrict__ b2,
    u16* __restrict__ pack, float* __restrict__ cvec)
{
    const int c = blockIdx.x;   // n-chunk (8 n each), 0..13
    const int b = blockIdx.y;   // 0..15
    const int t = threadIdx.x;  // 0..1023

    __shared__ __align__(16) float sf_t[HID][8];
    __shared__ __align__(16) float part[4][8][256];
    __shared__ __align__(16) float fsp[8][PROJ];
    __shared__ __align__(16) float hidp[2][8][DYN];
    __shared__ __align__(16) float hid[8][DYN];
    __shared__ __align__(16) float fsf_t[PROJ][8];
    __shared__ float cacc[8][4];

    const int g = t >> 8;
    const int p = t & 255;

    // step 1: load 8 support rows -> transposed LDS
    {
        const int nl = t >> 7;
        const int i0 = (t & 127) * 2;
        const int n = c * 8 + nl;
        float v0 = 0.f, v1 = 0.f;
        if (n < NQ) {
            const float* sp = support + (size_t)n * (BSZ * HID) + (size_t)b * HID + i0;
            const float2 a = *reinterpret_cast<const float2*>(sp);
            v0 = a.x; v1 = a.y;
        }
        sf_t[i0][nl] = v0;
        sf_t[i0 + 1][nl] = v1;
    }
    __syncthreads();

    // step 2: fs_proj partials
    {
        float acc[8];
        #pragma unroll
        for (int n = 0; n < 8; ++n) acc[n] = 0.f;
        const int ibase = g * 64;
        float w[64];
        #pragma unroll
        for (int j = 0; j < 64; ++j)
            w[j] = Ws[(size_t)(ibase + j) * PROJ + p];
        __builtin_amdgcn_sched_barrier(0);
        #pragma unroll
        for (int j = 0; j < 64; ++j) {
            const f32x4 s0 = *reinterpret_cast<const f32x4*>(&sf_t[ibase + j][0]);
            const f32x4 s1 = *reinterpret_cast<const f32x4*>(&sf_t[ibase + j][4]);
            acc[0] += s0[0] * w[j]; acc[1] += s0[1] * w[j];
            acc[2] += s0[2] * w[j]; acc[3] += s0[3] * w[j];
            acc[4] += s1[0] * w[j]; acc[5] += s1[1] * w[j];
            acc[6] += s1[2] * w[j]; acc[7] += s1[3] * w[j];
        }
        #pragma unroll
        for (int n = 0; n < 8; ++n) part[g][n][p] = acc[n];
    }
    __syncthreads();
    {
        const int na = t >> 8;
        const float bb = bsp[p];
        #pragma unroll
        for (int k = 0; k < 2; ++k) {
            const int n = na + k * 4;
            fsp[n][p] = part[0][n][p] + part[1][n][p] + part[2][n][p] + part[3][n][p] + bb;
        }
    }
    __syncthreads();

    // step 3: hidden
    {
        const int ph = t >> 9;
        const int n = (t >> 6) & 7;
        const int d = t & 63;
        float a = 0.f;
        const int pb0 = ph * 128;
        #pragma unroll
        for (int pb = 0; pb < 128; pb += 64) {
            float w[64];
            #pragma unroll
            for (int j = 0; j < 64; ++j)
                w[j] = W1[(size_t)(pb0 + pb + j) * DYN + d];
            __builtin_amdgcn_sched_barrier(0);
            #pragma unroll
            for (int j = 0; j < 64; j += 4) {
                const f32x4 s = *reinterpret_cast<const f32x4*>(&fsp[n][pb0 + pb + j]);
                a += s[0] * w[j] + s[1] * w[j + 1] + s[2] * w[j + 2] + s[3] * w[j + 3];
            }
        }
        hidp[ph][n][d] = a;
    }
    __syncthreads();
    if (t < 512) {
        const int n = t >> 6, d = t & 63;
        const float a = hidp[0][n][d] + hidp[1][n][d] + b1[d];
        hid[n][d] = a > 0.f ? a : 0.f;
    }
    __syncthreads();

    // step 4: pattern -> fs_feat + c partials
    {
        const int nh = t >> 8;
        const int n0 = nh * 2, n1 = nh * 2 + 1;
        const float bqv = bq[p];
        const float b2v = b2[p];
        float w[64];
        #pragma unroll
        for (int d = 0; d < 64; ++d) w[d] = W2[(size_t)d * PROJ + p];
        __builtin_amdgcn_sched_barrier(0);
        float a0 = 0.f, a1 = 0.f;
        #pragma unroll
        for (int d0 = 0; d0 < 64; d0 += 4) {
            const f32x4 h0 = *reinterpret_cast<const f32x4*>(&hid[n0][d0]);
            const f32x4 h1 = *reinterpret_cast<const f32x4*>(&hid[n1][d0]);
            a0 += h0[0] * w[d0] + h0[1] * w[d0 + 1] + h0[2] * w[d0 + 2] + h0[3] * w[d0 + 3];
            a1 += h1[0] * w[d0] + h1[1] * w[d0 + 1] + h1[2] * w[d0 + 2] + h1[3] * w[d0 + 3];
        }
        const float pat0 = tanhf(a0 + b2v);
        const float pat1 = tanhf(a1 + b2v);
        const float ff0 = (pat0 + 1.f) * fsp[n0][p];
        const float ff1 = (pat1 + 1.f) * fsp[n1][p];
        *reinterpret_cast<float2*>(&fsf_t[p][n0]) = make_float2(ff0, ff1);
        float cp0 = bqv * ff0, cp1 = bqv * ff1;
        for (int off = 32; off > 0; off >>= 1) {
            cp0 += __shfl_down(cp0, off);
            cp1 += __shfl_down(cp1, off);
        }
        const int lane = t & 63;
        const int ps = (t >> 6) & 3;
        if (lane == 0) { cacc[n0][ps] = cp0; cacc[n1][ps] = cp1; }
    }
    __syncthreads();
    if (t < 8) {
        const int n = c * 8 + t;
        if (n < NQ) cvec[b * NQ + n] = cacc[t][0] + cacc[t][1] + cacc[t][2] + cacc[t][3];
    }

    // step 5: Gt[n][h]
    {
        const int h = p;
        float acc[8];
        #pragma unroll
        for (int n = 0; n < 8; ++n) acc[n] = 0.f;
        const int pbase = g * 64;
        f32x4 wv4[16];
        #pragma unroll
        for (int k = 0; k < 16; ++k)
            wv4[k] = *reinterpret_cast<const f32x4*>(Wq + (size_t)h * PROJ + pbase + k * 4);
        __builtin_amdgcn_sched_barrier(0);
        #pragma unroll
        for (int k = 0; k < 16; ++k) {
            #pragma unroll
            for (int m = 0; m < 4; ++m) {
                const int pp = pbase + k * 4 + m;
                const float w = wv4[k][m];
                const f32x4 f0 = *reinterpret_cast<const f32x4*>(&fsf_t[pp][0]);
                const f32x4 f1 = *reinterpret_cast<const f32x4*>(&fsf_t[pp][4]);
                acc[0] += f0[0] * w; acc[1] += f0[1] * w;
                acc[2] += f0[2] * w; acc[3] += f0[3] * w;
                acc[4] += f1[0] * w; acc[5] += f1[1] * w;
                acc[6] += f1[2] * w; acc[7] += f1[3] * w;
            }
        }
        #pragma unroll
        for (int n = 0; n < 8; ++n) part[g][n][h] = acc[n];
    }
    __syncthreads();

    // final reduce + hi/lo bf16 pack
    {
        const int h = p;
        const int na = t >> 8;
        const int ks = h >> 5, quad = (h >> 3) & 3, j = h & 7;
        const int nt = c >> 1;
        #pragma unroll
        for (int k = 0; k < 2; ++k) {
            const int nl = na + k * 4;
            const int n = c * 8 + nl;
            float f = part[0][nl][h] + part[1][nl][h] + part[2][nl][h] + part[3][nl][h];
            if (n >= NQ) f = 0.f;
            const u16 hi = f2bf(f);
            const u16 lo = f2bf(f - bf2f(hi));
            const int nit = (c & 1) * 8 + nl;
            const int lane2 = quad * 16 + nit;
            const size_t base = ((((size_t)b * 2 + 0) * 8 + ks) * 8 + nt) * 512 + lane2 * 8 + j;
            pack[base] = hi;
            pack[base + (size_t)8 * 8 * 512] = lo;
        }
    }
}

// ---------------------------------------------------------------------------
// K2 v12: R8's 2-ks superstep main loop (best measured) + FUSED kfin
// reductions in the epilogue. Each block computes, per n, online-softmax
// partials over its 64 hw values {max, sum e, sum e*x, sum e*y, argmax idx}
// via quad shuffles (xor 16/32) + cross-wave LDS combine, written to a
// 3.2MB workspace. This lets us DELETE kfin's 41MB sim re-read (a whole
// ~55-60us latency-bound kernel) -- R5-R8 proved ksim's schedule is at its
// floor, so the remaining lever is algorithmic fusion.
// ---------------------------------------------------------------------------
__global__ __launch_bounds__(256, 2) void ksim(
    const float* __restrict__ qf,    // [6400][16][256] f32
    const u16* __restrict__ pack,
    const float* __restrict__ cvec,
    float* __restrict__ sim,         // -> out + 3200, [16][100][6400] f32
    float* __restrict__ gpart)       // [16][100][100 mc][5] f32
{
    const int mc = blockIdx.x;  // 0..99  (64 rows each)
    const int b  = blockIdx.y;  // 0..15
    const int wv = threadIdx.x >> 6;
    const int lane = threadIdx.x & 63;
    const int quad = lane >> 4, l16 = lane & 15;

    // 2 super-buffers; each 28 slots (s28 = s_*14 + kp*7 + nt), 28KB apiece
    __shared__ __align__(16) u16 sbuf[2][28][512];   // 56 KB
    __shared__ float spart[4][7][16][5];             // 8.75 KB (epilogue)

    const u16* pbase = pack + (size_t)b * 65536;

    #define STAGE2(KP, BUF)                                                         \
        do {                                                                        \
            _Pragma("unroll")                                                       \
            for (int i = 0; i < 7; ++i) {                                           \
                const int s28 = wv * 7 + i;                                         \
                const int s_ = s28 / 14;                                            \
                const int r_ = s28 % 14;                                            \
                const int ks_ = (KP) * 2 + r_ / 7;                                  \
                const int nt_ = r_ % 7;                                             \
                const u16* g_ = pbase + ((size_t)(s_ * 8 + ks_) * 8 + nt_) * 512    \
                                + (size_t)lane * 8;                                 \
                __builtin_amdgcn_global_load_lds(                                   \
                    (const __attribute__((address_space(1))) void*)g_,              \
                    (__attribute__((address_space(3))) void*)&sbuf[BUF][s28][0],    \
                    16, 0, 0);                                                      \
            }                                                                       \
        } while (0)

    f32x4 acc[7];
    #pragma unroll
    for (int nt = 0; nt < 7; ++nt) acc[nt] = (f32x4){0.f, 0.f, 0.f, 0.f};

    const int row = mc * 64 + wv * 16 + l16;
    const float* ap = qf + (size_t)row * (BSZ * HID) + b * HID + quad * 8;

    // ---- prologue: 16 A loads in ONE asm block, stage chunk 0, convert ----
    f32x4 af[16];
    {
        const float* p0 = ap + 0 * 32;
        const float* p1 = ap + 1 * 32;
        const float* p2 = ap + 2 * 32;
        const float* p3 = ap + 3 * 32;
        const float* p4 = ap + 4 * 32;
        const float* p5 = ap + 5 * 32;
        const float* p6 = ap + 6 * 32;
        const float* p7 = ap + 7 * 32;
        asm volatile(
            "global_load_dwordx4 %0, %16, off\n\t"
            "global_load_dwordx4 %1, %16, off offset:16\n\t"
            "global_load_dwordx4 %2, %17, off\n\t"
            "global_load_dwordx4 %3, %17, off offset:16\n\t"
            "global_load_dwordx4 %4, %18, off\n\t"
            "global_load_dwordx4 %5, %18, off offset:16\n\t"
            "global_load_dwordx4 %6, %19, off\n\t"
            "global_load_dwordx4 %7, %19, off offset:16\n\t"
            "global_load_dwordx4 %8, %20, off\n\t"
            "global_load_dwordx4 %9, %20, off offset:16\n\t"
            "global_load_dwordx4 %10, %21, off\n\t"
            "global_load_dwordx4 %11, %21, off offset:16\n\t"
            "global_load_dwordx4 %12, %22, off\n\t"
            "global_load_dwordx4 %13, %22, off offset:16\n\t"
            "global_load_dwordx4 %14, %23, off\n\t"
            "global_load_dwordx4 %15, %23, off offset:16\n\t"
            "s_waitcnt vmcnt(0)"
            : "=&v"(af[0]), "=&v"(af[1]), "=&v"(af[2]), "=&v"(af[3]),
              "=&v"(af[4]), "=&v"(af[5]), "=&v"(af[6]), "=&v"(af[7]),
              "=&v"(af[8]), "=&v"(af[9]), "=&v"(af[10]), "=&v"(af[11]),
              "=&v"(af[12]), "=&v"(af[13]), "=&v"(af[14]), "=&v"(af[15])
            : "v"(p0), "v"(p1), "v"(p2), "v"(p3),
              "v"(p4), "v"(p5), "v"(p6), "v"(p7));
    }
    STAGE2(0, 0);

    bf16x8 Ahi[8], Alo[8];
    #pragma unroll
    for (int ks = 0; ks < 8; ++ks) {
        #pragma unroll
        for (int j = 0; j < 4; ++j) {
            const float v0 = af[2 * ks][j];
            const __bf16 h0 = (__bf16)v0;
            Ahi[ks][j] = h0; Alo[ks][j] = (__bf16)(v0 - (float)h0);
            const float v1 = af[2 * ks + 1][j];
            const __bf16 h1 = (__bf16)v1;
            Ahi[ks][4 + j] = h1; Alo[ks][4 + j] = (__bf16)(v1 - (float)h1);
        }
    }
    __syncthreads();   // drains stage chunk 0

    #define KS_COMPUTE(KS, BUF)                                                      \
    {                                                                                \
        const int kp_ = (KS) & 1;                                                    \
        u16x8 uh[7];                                                                 \
        _Pragma("unroll")                                                            \
        for (int nt = 0; nt < 7; ++nt)                                               \
            uh[nt] = *reinterpret_cast<const u16x8*>(&sbuf[BUF][kp_ * 7 + nt][lane * 8]); \
        _Pragma("unroll")                                                            \
        for (int nt = 0; nt < 7; ++nt) {                                             \
            const bf16x8 bh = __builtin_bit_cast(bf16x8, uh[nt]);                    \
            acc[nt] = __builtin_amdgcn_mfma_f32_16x16x32_bf16(Ahi[KS], bh, acc[nt], 0, 0, 0); \
            acc[nt] = __builtin_amdgcn_mfma_f32_16x16x32_bf16(Alo[KS], bh, acc[nt], 0, 0, 0); \
        }                                                                            \
        u16x8 ul[7];                                                                 \
        _Pragma("unroll")                                                            \
        for (int nt = 0; nt < 7; ++nt)                                               \
            ul[nt] = *reinterpret_cast<const u16x8*>(&sbuf[BUF][14 + kp_ * 7 + nt][lane * 8]); \
        _Pragma("unroll")                                                            \
        for (int nt = 0; nt < 7; ++nt) {                                             \
            const bf16x8 bl = __builtin_bit_cast(bf16x8, ul[nt]);                    \
            acc[nt] = __builtin_amdgcn_mfma_f32_16x16x32_bf16(Ahi[KS], bl, acc[nt], 0, 0, 0); \
        }                                                                            \
    }

    STAGE2(1, 1);
    KS_COMPUTE(0, 0)
    KS_COMPUTE(1, 0)
    __syncthreads();
    STAGE2(2, 0);
    KS_COMPUTE(2, 1)
    KS_COMPUTE(3, 1)
    __syncthreads();
    STAGE2(3, 1);
    KS_COMPUTE(4, 0)
    KS_COMPUTE(5, 0)
    __syncthreads();
    KS_COMPUTE(6, 1)
    KS_COMPUTE(7, 1)

    #undef KS_COMPUTE
    #undef STAGE2

    // ---- fused epilogue: sim write + per-(block,n) softmax/argmax partials
    const int kbase = mc * 64 + wv * 16 + quad * 4;
    float fx4[4], fy4[4];
    #pragma unroll
    for (int r = 0; r < 4; ++r) {
        const int h = kbase + r;
        fx4[r] = (float)(h % WW) + 0.5f;
        fy4[r] = (float)(h / WW) + 0.5f;
    }
    #pragma unroll
    for (int nt = 0; nt < 7; ++nt) {
        const int n = nt * 16 + l16;
        const float cadd = (n < NQ) ? cvec[b * NQ + n] : 0.f;
        f32x4 o = acc[nt];
        o[0] += cadd; o[1] += cadd; o[2] += cadd; o[3] += cadd;
        if (n < NQ)
            *reinterpret_cast<f32x4*>(sim + (size_t)(b * NQ + n) * HWD + kbase) = o;

        // local max / first-occurrence argmax over this lane's 4 values
        float mx = o[0]; int mi = kbase;
        if (o[1] > mx) { mx = o[1]; mi = kbase + 1; }
        if (o[2] > mx) { mx = o[2]; mi = kbase + 2; }
        if (o[3] > mx) { mx = o[3]; mi = kbase + 3; }
        // reduce across quads (lanes l16, l16+16, +32, +48 hold same n)
        #pragma unroll
        for (int mm = 16; mm <= 32; mm <<= 1) {
            const float ov = __shfl_xor(mx, mm);
            const int oi = __shfl_xor(mi, mm);
            if (ov > mx || (ov == mx && oi < mi)) { mx = ov; mi = oi; }
        }
        // exp sums with the wave-level max
        float s1 = 0.f, sx = 0.f, sy = 0.f;
        #pragma unroll
        for (int r = 0; r < 4; ++r) {
            const float e = __expf(o[r] - mx);
            s1 += e; sx += e * fx4[r]; sy += e * fy4[r];
        }
        #pragma unroll
        for (int mm = 16; mm <= 32; mm <<= 1) {
            s1 += __shfl_xor(s1, mm);
            sx += __shfl_xor(sx, mm);
            sy += __shfl_xor(sy, mm);
        }
        if (quad == 0) {
            spart[wv][nt][l16][0] = mx;
            spart[wv][nt][l16][1] = s1;
            spart[wv][nt][l16][2] = sx;
            spart[wv][nt][l16][3] = sy;
            spart[wv][nt][l16][4] = __int_as_float(mi);
        }
    }
    __syncthreads();

    // cross-wave combine (ascending wv = ascending h -> first occurrence kept)
    {
        const int t = threadIdx.x;
        if (t < 112) {
            const int n = t, nt_ = t >> 4, l16_ = t & 15;
            float M  = spart[0][nt_][l16_][0];
            float S1 = spart[0][nt_][l16_][1];
            float SX = spart[0][nt_][l16_][2];
            float SY = spart[0][nt_][l16_][3];
            int   BI = __float_as_int(spart[0][nt_][l16_][4]);
            #pragma unroll
            for (int w = 1; w < 4; ++w) {
                const float m2 = spart[w][nt_][l16_][0];
                const float s2 = spart[w][nt_][l16_][1];
                const float x2 = spart[w][nt_][l16_][2];
                const float y2 = spart[w][nt_][l16_][3];
                const int  bi2 = __float_as_int(spart[w][nt_][l16_][4]);
                const float nM = fmaxf(M, m2);
                const float ea = __expf(M - nM), eb = __expf(m2 - nM);
                S1 = S1 * ea + s2 * eb;
                SX = SX * ea + x2 * eb;
                SY = SY * ea + y2 * eb;
                if (m2 > M || (m2 == M && bi2 < BI)) BI = bi2;
                M = nM;
            }
            if (n < NQ) {
                float* gp = gpart + ((size_t)(b * NQ + n) * 100 + mc) * 5;
                gp[0] = M; gp[1] = S1; gp[2] = SX; gp[3] = SY;
                gp[4] = __int_as_float(BI);
            }
        }
    }
}

// ---------------------------------------------------------------------------
// K3 v7 "kfin2": one wave per (b,n). Merges 100 per-block partials
// (rescale-merge, order-independent argmax tie-break), then reads ONLY the
// <=9 sim cells around the peak for the 3x3 window. Replaces the 41MB
// sim re-read kernel with ~4MB of reads total.
// ---------------------------------------------------------------------------
__global__ __launch_bounds__(64, 4) void kfin2(
    const float* __restrict__ sim,     // out + 3200
    const float* __restrict__ gpart,   // [16][100][100][5]
    float* __restrict__ out)
{
    const int bn = blockIdx.x;       // 0..1599 = b*100+n
    const int lane = threadIdx.x;    // 0..63
    const float* gp = gpart + (size_t)bn * 100 * 5;

    // lane covers mc = lane (always valid) and mc = 64+lane (lane < 36)
    float M, S1, SX, SY; int BI;
    {
        const float* p = gp + lane * 5;
        M = p[0]; S1 = p[1]; SX = p[2]; SY = p[3]; BI = __float_as_int(p[4]);
    }
    if (lane < 36) {
        const float* p = gp + (64 + lane) * 5;
        const float m2 = p[0], s2 = p[1], x2 = p[2], y2 = p[3];
        const int bi2 = __float_as_int(p[4]);
        const float nM = fmaxf(M, m2);
        const float ea = __expf(M - nM), eb = __expf(m2 - nM);
        S1 = S1 * ea + s2 * eb; SX = SX * ea + x2 * eb; SY = SY * ea + y2 * eb;
        if (m2 > M || (m2 == M && bi2 < BI)) BI = bi2;
        M = nM;
    }
    #pragma unroll
    for (int mm = 1; mm < 64; mm <<= 1) {
        const float m2 = __shfl_xor(M, mm);
        const float s2 = __shfl_xor(S1, mm);
        const float x2 = __shfl_xor(SX, mm);
        const float y2 = __shfl_xor(SY, mm);
        const int bi2 = __shfl_xor(BI, mm);
        const float nM = fmaxf(M, m2);
        const float ea = __expf(M - nM), eb = __expf(m2 - nM);
        S1 = S1 * ea + s2 * eb; SX = SX * ea + x2 * eb; SY = SY * ea + y2 * eb;
        if (m2 > M || (m2 == M && bi2 < BI)) BI = bi2;
        M = nM;
    }

    // 3x3 window around the peak: lanes 0..8 read one cell each
    const int xc = BI % WW, yc = BI / WW;
    float wl = 0.f, wx = 0.f, wy = 0.f;
    if (lane < 9) {
        const int xe = xc + (lane % 3) - 1;
        const int ye = yc + (lane / 3) - 1;
        if (xe >= 0 && xe < WW && ye >= 0 && ye < HH) {
            const float v = sim[(size_t)bn * HWD + ye * WW + xe];
            const float e = __expf(v - M);
            wl = e; wx = e * ((float)xe + 0.5f); wy = e * ((float)ye + 0.5f);
        }
    }
    #pragma unroll
    for (int mm = 1; mm < 16; mm <<= 1) {
        wl += __shfl_xor(wl, mm);
        wx += __shfl_xor(wx, mm);
        wy += __shfl_xor(wy, mm);
    }

    if (lane == 0) {
        const float invS = 1.f / S1;
        out[(size_t)bn * 2 + 0] = SX * invS / (float)WW;
        out[(size_t)bn * 2 + 1] = SY * invS / (float)HH;
        const float den = wl + 1e-10f * S1;
        const size_t pbase = 3200 + (size_t)BSZ * NQ * HWD;
        out[pbase + (size_t)bn * 2 + 0] = wx / den / (float)WW;
        out[pbase + (size_t)bn * 2 + 1] = wy / den / (float)HH;
    }
}

extern "C" void kernel_launch(void* const* d_in, const int* in_sizes, int n_in,
                              void* d_out, int out_size, void* d_ws, size_t ws_size,
                              hipStream_t stream) {
    const float* qf  = (const float*)d_in[0];   // query_feat  [6400][16][256] f32
    const float* sf  = (const float*)d_in[1];   // support_feat[100][16][256] f32
    // d_in[2], d_in[3] = h, w (fixed 80x80)
    const float* Wq  = (const float*)d_in[4];
    const float* bq  = (const float*)d_in[5];
    const float* Ws  = (const float*)d_in[6];
    const float* bsp = (const float*)d_in[7];
    const float* W1  = (const float*)d_in[8];
    const float* b1  = (const float*)d_in[9];
    const float* W2  = (const float*)d_in[10];
    const float* b2  = (const float*)d_in[11];

    u16*   pack  = (u16*)d_ws;                          // 2,097,152 B
    float* cvec  = (float*)((char*)d_ws + 2097152);     //     6,400 B
    float* gpart = (float*)((char*)d_ws + 2103552);     // 3,200,000 B
    float* out   = (float*)d_out;
    float* sim   = out + 3200;                          // similarity region, f32

    kpre<<<dim3(14, 16), 1024, 0, stream>>>(sf, Wq, bq, Ws, bsp, W1, b1, W2, b2, pack, cvec);
    ksim<<<dim3(100, 16), 256, 0, stream>>>(qf, pack, cvec, sim, gpart);
    kfin2<<<1600, 64, 0, stream>>>(sim, gpart, out);
}

// Round 10
// 251.056 us; speedup vs baseline: 1.0660x; 1.0660x over previous
//
#include <hip/hip_runtime.h>

#define HID 256
#define PROJ 256
#define DYN 64
#define HWD 6400
#define BSZ 16
#define NQ 100
#define HH 80
#define WW 80

typedef unsigned short u16;
typedef u16 u16x8 __attribute__((ext_vector_type(8)));
typedef __bf16 bf16x8 __attribute__((ext_vector_type(8)));
typedef float f32x4 __attribute__((ext_vector_type(4)));

__device__ __forceinline__ float bf2f(u16 h) {
    union { unsigned u; float f; } c; c.u = ((unsigned)h) << 16; return c.f;
}
__device__ __forceinline__ u16 f2bf(float f) {
    union { float f; unsigned u; } c; c.f = f;
    return (u16)((c.u + 0x7FFFu + ((c.u >> 16) & 1u)) >> 16);
}

// ---------------------------------------------------------------------------
// K1 v3 (unchanged): 1024 thr, 4-way K-split, pinned weight batches.
// ---------------------------------------------------------------------------
__global__ __launch_bounds__(1024, 1) void kpre(
    const float* __restrict__ support,   // [100][16][256] f32
    const float* __restrict__ Wq, const float* __restrict__ bq,
    const float* __restrict__ Ws, const float* __restrict__ bsp,
    const float* __restrict__ W1, const float* __restrict__ b1,
    const float* __restrict__ W2, const float* __restrict__ b2,
    u16* __restrict__ pack, float* __restrict__ cvec)
{
    const int c = blockIdx.x;   // n-chunk (8 n each), 0..13
    const int b = blockIdx.y;   // 0..15
    const int t = threadIdx.x;  // 0..1023

    __shared__ __align__(16) float sf_t[HID][8];
    __shared__ __align__(16) float part[4][8][256];
    __shared__ __align__(16) float fsp[8][PROJ];
    __shared__ __align__(16) float hidp[2][8][DYN];
    __shared__ __align__(16) float hid[8][DYN];
    __shared__ __align__(16) float fsf_t[PROJ][8];
    __shared__ float cacc[8][4];

    const int g = t >> 8;
    const int p = t & 255;

    // step 1: load 8 support rows -> transposed LDS
    {
        const int nl = t >> 7;
        const int i0 = (t & 127) * 2;
        const int n = c * 8 + nl;
        float v0 = 0.f, v1 = 0.f;
        if (n < NQ) {
            const float* sp = support + (size_t)n * (BSZ * HID) + (size_t)b * HID + i0;
            const float2 a = *reinterpret_cast<const float2*>(sp);
            v0 = a.x; v1 = a.y;
        }
        sf_t[i0][nl] = v0;
        sf_t[i0 + 1][nl] = v1;
    }
    __syncthreads();

    // step 2: fs_proj partials
    {
        float acc[8];
        #pragma unroll
        for (int n = 0; n < 8; ++n) acc[n] = 0.f;
        const int ibase = g * 64;
        float w[64];
        #pragma unroll
        for (int j = 0; j < 64; ++j)
            w[j] = Ws[(size_t)(ibase + j) * PROJ + p];
        __builtin_amdgcn_sched_barrier(0);
        #pragma unroll
        for (int j = 0; j < 64; ++j) {
            const f32x4 s0 = *reinterpret_cast<const f32x4*>(&sf_t[ibase + j][0]);
            const f32x4 s1 = *reinterpret_cast<const f32x4*>(&sf_t[ibase + j][4]);
            acc[0] += s0[0] * w[j]; acc[1] += s0[1] * w[j];
            acc[2] += s0[2] * w[j]; acc[3] += s0[3] * w[j];
            acc[4] += s1[0] * w[j]; acc[5] += s1[1] * w[j];
            acc[6] += s1[2] * w[j]; acc[7] += s1[3] * w[j];
        }
        #pragma unroll
        for (int n = 0; n < 8; ++n) part[g][n][p] = acc[n];
    }
    __syncthreads();
    {
        const int na = t >> 8;
        const float bb = bsp[p];
        #pragma unroll
        for (int k = 0; k < 2; ++k) {
            const int n = na + k * 4;
            fsp[n][p] = part[0][n][p] + part[1][n][p] + part[2][n][p] + part[3][n][p] + bb;
        }
    }
    __syncthreads();

    // step 3: hidden
    {
        const int ph = t >> 9;
        const int n = (t >> 6) & 7;
        const int d = t & 63;
        float a = 0.f;
        const int pb0 = ph * 128;
        #pragma unroll
        for (int pb = 0; pb < 128; pb += 64) {
            float w[64];
            #pragma unroll
            for (int j = 0; j < 64; ++j)
                w[j] = W1[(size_t)(pb0 + pb + j) * DYN + d];
            __builtin_amdgcn_sched_barrier(0);
            #pragma unroll
            for (int j = 0; j < 64; j += 4) {
                const f32x4 s = *reinterpret_cast<const f32x4*>(&fsp[n][pb0 + pb + j]);
                a += s[0] * w[j] + s[1] * w[j + 1] + s[2] * w[j + 2] + s[3] * w[j + 3];
            }
        }
        hidp[ph][n][d] = a;
    }
    __syncthreads();
    if (t < 512) {
        const int n = t >> 6, d = t & 63;
        const float a = hidp[0][n][d] + hidp[1][n][d] + b1[d];
        hid[n][d] = a > 0.f ? a : 0.f;
    }
    __syncthreads();

    // step 4: pattern -> fs_feat + c partials
    {
        const int nh = t >> 8;
        const int n0 = nh * 2, n1 = nh * 2 + 1;
        const float bqv = bq[p];
        const float b2v = b2[p];
        float w[64];
        #pragma unroll
        for (int d = 0; d < 64; ++d) w[d] = W2[(size_t)d * PROJ + p];
        __builtin_amdgcn_sched_barrier(0);
        float a0 = 0.f, a1 = 0.f;
        #pragma unroll
        for (int d0 = 0; d0 < 64; d0 += 4) {
            const f32x4 h0 = *reinterpret_cast<const f32x4*>(&hid[n0][d0]);
            const f32x4 h1 = *reinterpret_cast<const f32x4*>(&hid[n1][d0]);
            a0 += h0[0] * w[d0] + h0[1] * w[d0 + 1] + h0[2] * w[d0 + 2] + h0[3] * w[d0 + 3];
            a1 += h1[0] * w[d0] + h1[1] * w[d0 + 1] + h1[2] * w[d0 + 2] + h1[3] * w[d0 + 3];
        }
        const float pat0 = tanhf(a0 + b2v);
        const float pat1 = tanhf(a1 + b2v);
        const float ff0 = (pat0 + 1.f) * fsp[n0][p];
        const float ff1 = (pat1 + 1.f) * fsp[n1][p];
        *reinterpret_cast<float2*>(&fsf_t[p][n0]) = make_float2(ff0, ff1);
        float cp0 = bqv * ff0, cp1 = bqv * ff1;
        for (int off = 32; off > 0; off >>= 1) {
            cp0 += __shfl_down(cp0, off);
            cp1 += __shfl_down(cp1, off);
        }
        const int lane = t & 63;
        const int ps = (t >> 6) & 3;
        if (lane == 0) { cacc[n0][ps] = cp0; cacc[n1][ps] = cp1; }
    }
    __syncthreads();
    if (t < 8) {
        const int n = c * 8 + t;
        if (n < NQ) cvec[b * NQ + n] = cacc[t][0] + cacc[t][1] + cacc[t][2] + cacc[t][3];
    }

    // step 5: Gt[n][h]
    {
        const int h = p;
        float acc[8];
        #pragma unroll
        for (int n = 0; n < 8; ++n) acc[n] = 0.f;
        const int pbase = g * 64;
        f32x4 wv4[16];
        #pragma unroll
        for (int k = 0; k < 16; ++k)
            wv4[k] = *reinterpret_cast<const f32x4*>(Wq + (size_t)h * PROJ + pbase + k * 4);
        __builtin_amdgcn_sched_barrier(0);
        #pragma unroll
        for (int k = 0; k < 16; ++k) {
            #pragma unroll
            for (int m = 0; m < 4; ++m) {
                const int pp = pbase + k * 4 + m;
                const float w = wv4[k][m];
                const f32x4 f0 = *reinterpret_cast<const f32x4*>(&fsf_t[pp][0]);
                const f32x4 f1 = *reinterpret_cast<const f32x4*>(&fsf_t[pp][4]);
                acc[0] += f0[0] * w; acc[1] += f0[1] * w;
                acc[2] += f0[2] * w; acc[3] += f0[3] * w;
                acc[4] += f1[0] * w; acc[5] += f1[1] * w;
                acc[6] += f1[2] * w; acc[7] += f1[3] * w;
            }
        }
        #pragma unroll
        for (int n = 0; n < 8; ++n) part[g][n][h] = acc[n];
    }
    __syncthreads();

    // final reduce + hi/lo bf16 pack
    {
        const int h = p;
        const int na = t >> 8;
        const int ks = h >> 5, quad = (h >> 3) & 3, j = h & 7;
        const int nt = c >> 1;
        #pragma unroll
        for (int k = 0; k < 2; ++k) {
            const int nl = na + k * 4;
            const int n = c * 8 + nl;
            float f = part[0][nl][h] + part[1][nl][h] + part[2][nl][h] + part[3][nl][h];
            if (n >= NQ) f = 0.f;
            const u16 hi = f2bf(f);
            const u16 lo = f2bf(f - bf2f(hi));
            const int nit = (c & 1) * 8 + nl;
            const int lane2 = quad * 16 + nit;
            const size_t base = ((((size_t)b * 2 + 0) * 8 + ks) * 8 + nt) * 512 + lane2 * 8 + j;
            pack[base] = hi;
            pack[base + (size_t)8 * 8 * 512] = lo;
        }
    }
}

// ---------------------------------------------------------------------------
// K2 v13 = R8's v11 REVERTED VERBATIM (best measured ksim: 62.2-63.1us).
// R9 post-mortem: fusing softmax partials into the epilogue slowed the MAIN
// LOOP itself (MfmaUtil 10.3->7.5, +26us) via codegen perturbation + barrier
// + scattered writes. Fusion abandoned; 2-ks superstep loop restored.
// ---------------------------------------------------------------------------
__global__ __launch_bounds__(256, 2) void ksim(
    const float* __restrict__ qf,    // [6400][16][256] f32
    const u16* __restrict__ pack,
    const float* __restrict__ cvec,
    float* __restrict__ sim)         // -> out + 3200, [16][100][6400] f32
{
    const int mc = blockIdx.x;  // 0..99  (64 rows each)
    const int b  = blockIdx.y;  // 0..15
    const int wv = threadIdx.x >> 6;
    const int lane = threadIdx.x & 63;
    const int quad = lane >> 4, l16 = lane & 15;

    // 2 super-buffers; each 28 slots (s28 = s_*14 + kp*7 + nt), 28KB apiece
    __shared__ __align__(16) u16 sbuf[2][28][512];   // 56 KB

    const u16* pbase = pack + (size_t)b * 65536;

    #define STAGE2(KP, BUF)                                                         \
        do {                                                                        \
            _Pragma("unroll")                                                       \
            for (int i = 0; i < 7; ++i) {                                           \
                const int s28 = wv * 7 + i;                                         \
                const int s_ = s28 / 14;                                            \
                const int r_ = s28 % 14;                                            \
                const int ks_ = (KP) * 2 + r_ / 7;                                  \
                const int nt_ = r_ % 7;                                             \
                const u16* g_ = pbase + ((size_t)(s_ * 8 + ks_) * 8 + nt_) * 512    \
                                + (size_t)lane * 8;                                 \
                __builtin_amdgcn_global_load_lds(                                   \
                    (const __attribute__((address_space(1))) void*)g_,              \
                    (__attribute__((address_space(3))) void*)&sbuf[BUF][s28][0],    \
                    16, 0, 0);                                                      \
            }                                                                       \
        } while (0)

    f32x4 acc[7];
    #pragma unroll
    for (int nt = 0; nt < 7; ++nt) acc[nt] = (f32x4){0.f, 0.f, 0.f, 0.f};

    const int row = mc * 64 + wv * 16 + l16;
    const float* ap = qf + (size_t)row * (BSZ * HID) + b * HID + quad * 8;

    // ---- prologue: 16 A loads in ONE asm block, stage chunk 0, convert ----
    f32x4 af[16];
    {
        const float* p0 = ap + 0 * 32;
        const float* p1 = ap + 1 * 32;
        const float* p2 = ap + 2 * 32;
        const float* p3 = ap + 3 * 32;
        const float* p4 = ap + 4 * 32;
        const float* p5 = ap + 5 * 32;
        const float* p6 = ap + 6 * 32;
        const float* p7 = ap + 7 * 32;
        asm volatile(
            "global_load_dwordx4 %0, %16, off\n\t"
            "global_load_dwordx4 %1, %16, off offset:16\n\t"
            "global_load_dwordx4 %2, %17, off\n\t"
            "global_load_dwordx4 %3, %17, off offset:16\n\t"
            "global_load_dwordx4 %4, %18, off\n\t"
            "global_load_dwordx4 %5, %18, off offset:16\n\t"
            "global_load_dwordx4 %6, %19, off\n\t"
            "global_load_dwordx4 %7, %19, off offset:16\n\t"
            "global_load_dwordx4 %8, %20, off\n\t"
            "global_load_dwordx4 %9, %20, off offset:16\n\t"
            "global_load_dwordx4 %10, %21, off\n\t"
            "global_load_dwordx4 %11, %21, off offset:16\n\t"
            "global_load_dwordx4 %12, %22, off\n\t"
            "global_load_dwordx4 %13, %22, off offset:16\n\t"
            "global_load_dwordx4 %14, %23, off\n\t"
            "global_load_dwordx4 %15, %23, off offset:16\n\t"
            "s_waitcnt vmcnt(0)"
            : "=&v"(af[0]), "=&v"(af[1]), "=&v"(af[2]), "=&v"(af[3]),
              "=&v"(af[4]), "=&v"(af[5]), "=&v"(af[6]), "=&v"(af[7]),
              "=&v"(af[8]), "=&v"(af[9]), "=&v"(af[10]), "=&v"(af[11]),
              "=&v"(af[12]), "=&v"(af[13]), "=&v"(af[14]), "=&v"(af[15])
            : "v"(p0), "v"(p1), "v"(p2), "v"(p3),
              "v"(p4), "v"(p5), "v"(p6), "v"(p7));
    }
    STAGE2(0, 0);

    bf16x8 Ahi[8], Alo[8];
    #pragma unroll
    for (int ks = 0; ks < 8; ++ks) {
        #pragma unroll
        for (int j = 0; j < 4; ++j) {
            const float v0 = af[2 * ks][j];
            const __bf16 h0 = (__bf16)v0;
            Ahi[ks][j] = h0; Alo[ks][j] = (__bf16)(v0 - (float)h0);
            const float v1 = af[2 * ks + 1][j];
            const __bf16 h1 = (__bf16)v1;
            Ahi[ks][4 + j] = h1; Alo[ks][4 + j] = (__bf16)(v1 - (float)h1);
        }
    }
    __syncthreads();   // drains stage chunk 0

    #define KS_COMPUTE(KS, BUF)                                                      \
    {                                                                                \
        const int kp_ = (KS) & 1;                                                    \
        u16x8 uh[7];                                                                 \
        _Pragma("unroll")                                                            \
        for (int nt = 0; nt < 7; ++nt)                                               \
            uh[nt] = *reinterpret_cast<const u16x8*>(&sbuf[BUF][kp_ * 7 + nt][lane * 8]); \
        _Pragma("unroll")                                                            \
        for (int nt = 0; nt < 7; ++nt) {                                             \
            const bf16x8 bh = __builtin_bit_cast(bf16x8, uh[nt]);                    \
            acc[nt] = __builtin_amdgcn_mfma_f32_16x16x32_bf16(Ahi[KS], bh, acc[nt], 0, 0, 0); \
            acc[nt] = __builtin_amdgcn_mfma_f32_16x16x32_bf16(Alo[KS], bh, acc[nt], 0, 0, 0); \
        }                                                                            \
        u16x8 ul[7];                                                                 \
        _Pragma("unroll")                                                            \
        for (int nt = 0; nt < 7; ++nt)                                               \
            ul[nt] = *reinterpret_cast<const u16x8*>(&sbuf[BUF][14 + kp_ * 7 + nt][lane * 8]); \
        _Pragma("unroll")                                                            \
        for (int nt = 0; nt < 7; ++nt) {                                             \
            const bf16x8 bl = __builtin_bit_cast(bf16x8, ul[nt]);                    \
            acc[nt] = __builtin_amdgcn_mfma_f32_16x16x32_bf16(Ahi[KS], bl, acc[nt], 0, 0, 0); \
        }                                                                            \
    }

    STAGE2(1, 1);
    KS_COMPUTE(0, 0)
    KS_COMPUTE(1, 0)
    __syncthreads();
    STAGE2(2, 0);
    KS_COMPUTE(2, 1)
    KS_COMPUTE(3, 1)
    __syncthreads();
    STAGE2(3, 1);
    KS_COMPUTE(4, 0)
    KS_COMPUTE(5, 0)
    __syncthreads();
    KS_COMPUTE(6, 1)
    KS_COMPUTE(7, 1)

    #undef KS_COMPUTE
    #undef STAGE2

    // epilogue: D row (k-dim) = quad*4 + r, col (n) = l16
    const int kbase = mc * 64 + wv * 16 + quad * 4;
    #pragma unroll
    for (int nt = 0; nt < 7; ++nt) {
        const int n = nt * 16 + l16;
        if (n >= NQ) continue;
        const float cadd = cvec[b * NQ + n];
        f32x4 o = acc[nt];
        o[0] += cadd; o[1] += cadd; o[2] += cadd; o[3] += cadd;
        *reinterpret_cast<f32x4*>(sim + (size_t)(b * NQ + n) * HWD + kbase) = o;
    }
}

// ---------------------------------------------------------------------------
// K3 v8: FOUR waves per (b,n) row (was 2). kfin measured ~20us via the R9
// delta (41MB read at only ~2 TB/s -> occupancy-limited: 3200 waves =
// 3.1/SIMD). 6400 waves (6.25/SIMD) doubles the loads in flight. Chunk
// split 7/6/6/6; cross-wave combine via LDS; argmax merge is value-then-
// smaller-index, order-independent (first-occurrence preserved).
// ---------------------------------------------------------------------------
__global__ __launch_bounds__(256, 2) void kfin(
    const float* __restrict__ sim,   // out + 3200
    float* __restrict__ out)         // f32 outputs, concatenated
{
    const int bn = blockIdx.x;       // 0..1599
    const int w = threadIdx.x >> 6;  // 0..3
    const int lane = threadIdx.x & 63;
    const float* src = sim + (size_t)bn * HWD;

    __shared__ float redf[4][8];

    const int base = (w == 0) ? 0 : (7 + (w - 1) * 6);   // 0,7,13,19
    const int cnt  = (w == 0) ? 7 : 6;

    f32x4 v[7];
    #pragma unroll
    for (int j = 0; j < 7; ++j)
        if (j < cnt)
            v[j] = *reinterpret_cast<const f32x4*>(src + (base + j) * 256 + lane * 4);
    __builtin_amdgcn_sched_barrier(0);

    // phase A: local max / first-occurrence argmax, then global via LDS
    float bv = -3.4e38f; int bi = 0x7FFFFFFF;
    #pragma unroll
    for (int j = 0; j < 7; ++j) {
        if (j < cnt) {
            #pragma unroll
            for (int k = 0; k < 4; ++k) {
                if (v[j][k] > bv) { bv = v[j][k]; bi = (base + j) * 256 + lane * 4 + k; }
            }
        }
    }
    #pragma unroll
    for (int m = 1; m < 64; m <<= 1) {
        const float ov = __shfl_xor(bv, m);
        const int oi = __shfl_xor(bi, m);
        if (ov > bv || (ov == bv && oi < bi)) { bv = ov; bi = oi; }
    }
    if (lane == 0) { redf[w][0] = bv; redf[w][1] = __int_as_float(bi); }
    __syncthreads();
    {
        float M = redf[0][0]; int I = __float_as_int(redf[0][1]);
        #pragma unroll
        for (int ww = 1; ww < 4; ++ww) {
            const float m2 = redf[ww][0];
            const int i2 = __float_as_int(redf[ww][1]);
            if (m2 > M || (m2 == M && i2 < I)) { M = m2; I = i2; }
        }
        bv = M; bi = I;
    }
    const int xc = bi % WW, yc = bi / WW;

    // phase B: exp sums + 3x3 window sums
    float s1 = 0.f, sx = 0.f, sy = 0.f;
    float wl = 0.f, wx = 0.f, wyv = 0.f;
    const int g0 = base * 256 + lane * 4;
    int x = g0 % WW, y = g0 / WW;
    #pragma unroll
    for (int j = 0; j < 7; ++j) {
        if (j < cnt) {
            #pragma unroll
            for (int k = 0; k < 4; ++k) {
                int xe = x + k, ye = y;
                if (xe >= WW) { xe -= WW; ye += 1; }
                const float e = __expf(v[j][k] - bv);
                const float fx = (float)xe + 0.5f;
                const float fy = (float)ye + 0.5f;
                s1 += e; sx += e * fx; sy += e * fy;
                const int dx = xe - xc, dy = ye - yc;
                const bool inw = (dx >= -1 && dx <= 1 && dy >= -1 && dy <= 1);
                const float ew = inw ? e : 0.f;
                wl += ew; wx += ew * fx; wyv += ew * fy;
            }
        }
        x += 16; y += 3;
        if (x >= WW) { x -= WW; y += 1; }
    }
    #pragma unroll
    for (int m = 1; m < 64; m <<= 1) {
        s1 += __shfl_xor(s1, m);
        sx += __shfl_xor(sx, m);
        sy += __shfl_xor(sy, m);
        wl += __shfl_xor(wl, m);
        wx += __shfl_xor(wx, m);
        wyv += __shfl_xor(wyv, m);
    }
    if (lane == 0) {
        redf[w][2] = s1; redf[w][3] = sx; redf[w][4] = sy;
        redf[w][5] = wl; redf[w][6] = wx; redf[w][7] = wyv;
    }
    __syncthreads();

    if (w == 0 && lane == 0) {
        float S1 = 0.f, SX = 0.f, SY = 0.f, WL = 0.f, WX = 0.f, WY = 0.f;
        #pragma unroll
        for (int ww = 0; ww < 4; ++ww) {
            S1 += redf[ww][2]; SX += redf[ww][3]; SY += redf[ww][4];
            WL += redf[ww][5]; WX += redf[ww][6]; WY += redf[ww][7];
        }
        const float invS = 1.f / S1;
        out[(size_t)bn * 2 + 0] = SX * invS / (float)WW;
        out[(size_t)bn * 2 + 1] = SY * invS / (float)HH;
        const float den = WL + 1e-10f * S1;
        const size_t pbase = 3200 + (size_t)BSZ * NQ * HWD;
        out[pbase + (size_t)bn * 2 + 0] = WX / den / (float)WW;
        out[pbase + (size_t)bn * 2 + 1] = WY / den / (float)HH;
    }
}

extern "C" void kernel_launch(void* const* d_in, const int* in_sizes, int n_in,
                              void* d_out, int out_size, void* d_ws, size_t ws_size,
                              hipStream_t stream) {
    const float* qf  = (const float*)d_in[0];   // query_feat  [6400][16][256] f32
    const float* sf  = (const float*)d_in[1];   // support_feat[100][16][256] f32
    // d_in[2], d_in[3] = h, w (fixed 80x80)
    const float* Wq  = (const float*)d_in[4];
    const float* bq  = (const float*)d_in[5];
    const float* Ws  = (const float*)d_in[6];
    const float* bsp = (const float*)d_in[7];
    const float* W1  = (const float*)d_in[8];
    const float* b1  = (const float*)d_in[9];
    const float* W2  = (const float*)d_in[10];
    const float* b2  = (const float*)d_in[11];

    u16*   pack  = (u16*)d_ws;                         // 2,097,152 B
    float* cvec  = (float*)((char*)d_ws + 2097152);    //     6,400 B
    float* out   = (float*)d_out;
    float* sim   = out + 3200;                         // similarity region, f32

    kpre<<<dim3(14, 16), 1024, 0, stream>>>(sf, Wq, bq, Ws, bsp, W1, b1, W2, b2, pack, cvec);
    ksim<<<dim3(100, 16), 256, 0, stream>>>(qf, pack, cvec, sim);
    kfin<<<1600, 256, 0, stream>>>(sim, out);
}